// Round 16
// baseline (13254.887 us; speedup 1.0000x reference)
//
#include <hip/hip_runtime.h>
#include <math.h>

#define QQ 512
#define NN 1000
#define HHID 1024
#define HPAD 1024   // padded row stride for h trajectories (X uses 1024 too)
#define CCON 128
#define G4 4000
#define LAYERS 8
#define TC 64       // timestep chunk (gate-GEMM granularity)
#define CHUNKS (QQ / TC)            // 8
#define LB 125      // blocks per layer (8 neurons each, 512 thr, 1 n/wave)

__device__ inline float wred_min(float v){ for(int o=32;o;o>>=1) v=fminf(v,__shfl_xor(v,o)); return v; }
__device__ inline float wred_max(float v){ for(int o=32;o;o>>=1) v=fmaxf(v,__shfl_xor(v,o)); return v; }
__device__ inline float wred_sum(float v){ for(int o=32;o;o>>=1) v+=__shfl_xor(v,o); return v; }

// ---------------- generic NT GEMM (X prologue only) ----------------
__global__ __launch_bounds__(256) void gemm_nt(
    const float* __restrict__ A, const float* __restrict__ B,
    const float* __restrict__ bias1,
    float* __restrict__ C, int M, int K, int R, int lda, int ldc) {
  __shared__ float As[16][65];
  __shared__ float Bs[16][65];
  int tid = threadIdx.x;
  int tx = tid & 15, ty = tid >> 4;
  int m0 = blockIdx.y * 64, r0 = blockIdx.x * 64;
  float acc[4][4] = {};
  for (int k0 = 0; k0 < K; k0 += 16) {
#pragma unroll
    for (int i = 0; i < 4; i++) {
      int idx = tid + 256 * i;
      int ml = idx >> 4, kl = idx & 15;
      int m = m0 + ml, k = k0 + kl;
      As[kl][ml] = (m < M && k < K) ? A[(size_t)m * lda + k] : 0.f;
      int r = r0 + ml;
      Bs[kl][ml] = (r < R && k < K) ? B[(size_t)r * K + k] : 0.f;
    }
    __syncthreads();
#pragma unroll
    for (int kk = 0; kk < 16; kk++) {
      float a[4], b[4];
#pragma unroll
      for (int i = 0; i < 4; i++) a[i] = As[kk][ty * 4 + i];
#pragma unroll
      for (int j = 0; j < 4; j++) b[j] = Bs[kk][tx * 4 + j];
#pragma unroll
      for (int i = 0; i < 4; i++)
#pragma unroll
        for (int j = 0; j < 4; j++) acc[i][j] += a[i] * b[j];
    }
    __syncthreads();
  }
#pragma unroll
  for (int i = 0; i < 4; i++) {
    int m = m0 + ty * 4 + i;
    if (m >= M) continue;
#pragma unroll
    for (int j = 0; j < 4; j++) {
      int r = r0 + tx * 4 + j;
      if (r >= R) continue;
      float v = acc[i][j];
      if (bias1) v += bias1[r];
      C[(size_t)m * ldc + r] = v;
    }
  }
}

// -------- single persistent dataflow pipeline: 8 layers x 125 blocks -----
// Block = (layer, blk); 512 thr = 8 waves, wave owns neuron n = blk*8+wave.
// W_hh preloaded ONCE into 64 pinned VGPRs; cell state register-resident
// for all 512 steps. Per chunk c: wait prev-layer flags >= (c+1)*64, run
// the LDS-tiled 64x32xkin gate GEMM (round-15), then 64 recurrence steps
// with wave-0 flag polling + LDS go release. Relaxed sc1 atomics for all
// intra-dispatch cross-block data; NO fences (agent acquire fence =
// buffer_inv = full L2 invalidate, round-3 lesson). Weights/bias/X are
// kernel inputs or prev-dispatch data -> plain cached loads.
// Capacity: __launch_bounds__(512,4) caps VGPR at 128; LDS ~37.6KB -> 4
// blocks/CU -> 1024 >= 1000 all resident. Partial residency degrades to
// layer-serial (flags persist after exit) -- no deadlock.
struct PipeArgs {
  const float* X;                       // [QQ][HPAD]
  const float* Wih0; const float* Whh0; // [G4][HHID], [G4][NN]
  const float* bih0; const float* bhh0;
  const float* Wih; const float* Whh;   // [7][G4][NN]
  const float* bih; const float* bhh;   // [7][G4]
  float* H;                             // [LAYERS][QQ][HPAD]
  int* flags;                           // [LAYERS][128]
};

__global__ __launch_bounds__(512, 4) void lstm_pipe(PipeArgs a) {
  int layer = blockIdx.x / LB;
  int blk = blockIdx.x - layer * LB;
  __shared__ float As[64][65];   // 16.6 KB  Hin-chunk tile
  __shared__ float Bs[32][65];   //  8.3 KB  W_ih gate-row tile
  __shared__ float gl[TC * 32];  //  8.0 KB  gates gl[tt*32 + q*8 + w]
  __shared__ float hs[1024];     //  4.0 KB  h broadcast
  __shared__ int go[TC];
  __shared__ int goC;
  int tid = threadIdx.x;
  int wave = tid >> 6, lane = tid & 63;
  int n = blk * 8 + wave;        // 0..999, always valid (125*8 = 1000)

  int kin = (layer == 0) ? HHID : NN;
  const float* WihL = (layer == 0) ? a.Wih0 : a.Wih + (size_t)(layer - 1) * G4 * NN;
  const float* WhhL = (layer == 0) ? a.Whh0 : a.Whh + (size_t)(layer - 1) * G4 * NN;
  const float* b1 = (layer == 0) ? a.bih0 : a.bih + (size_t)(layer - 1) * G4;
  const float* b2 = (layer == 0) ? a.bhh0 : a.bhh + (size_t)(layer - 1) * G4;
  const float* Hin = (layer == 0) ? a.X : a.H + (size_t)(layer - 1) * QQ * HPAD;
  float* Hout = a.H + (size_t)layer * QQ * HPAD;
  int* fown = a.flags + layer * 128;
  int* fprev = a.flags + (layer - 1) * 128;

  // init LDS
  if (tid >= 488) hs[512 + tid] = 0.f;   // zero pad 1000..1023
  if (tid < TC) go[tid] = 0;
  if (tid == 0) goC = 0;

  // Preload W_hh rows once: wreg[q][it] = Whh[q*1000+n][it*64+lane]
  float wreg[4][16];
#pragma unroll
  for (int q = 0; q < 4; q++) {
    const float* wr = WhhL + (size_t)(q * NN + n) * NN;
#pragma unroll
    for (int it = 0; it < 16; it++) {
      int k = it * 64 + lane;
      wreg[q][it] = (k < NN) ? wr[k] : 0.f;
    }
  }
#pragma unroll
  for (int q = 0; q < 4; q++)
#pragma unroll
    for (int it = 0; it < 16; it++)
      asm volatile("" : "+v"(wreg[q][it]));  // keep register-resident

  // Bias for recurrence neuron n (wave-indexed) is inside gl already;
  // Phase A thread-neuron bias (w8-indexed), hoisted once:
  int w8 = tid & 7, ttA = tid >> 3;          // Phase A thread coords
  int nbA = blk * 8 + w8;
  float pbA[4];
#pragma unroll
  for (int q = 0; q < 4; q++)
    pbA[q] = b1[q * NN + nbA] + b2[q * NN + nbA];

  __syncthreads();

  float creg = 0.f;

  for (int c = 0; c < CHUNKS; c++) {
    int t0 = c * TC;
    // ---- wait: prev layer finished chunk c (flag >= t0+64) ----
    if (layer > 0) {
      int need = t0 + TC;
      if (wave == 0) {
        for (;;) {
          int ok = 1;
          if (lane < LB)
            ok &= (__hip_atomic_load(&fprev[lane], __ATOMIC_RELAXED,
                                     __HIP_MEMORY_SCOPE_AGENT) >= need);
          if (lane < LB - 64)
            ok &= (__hip_atomic_load(&fprev[64 + lane], __ATOMIC_RELAXED,
                                     __HIP_MEMORY_SCOPE_AGENT) >= need);
          if (__all(ok)) break;
          __builtin_amdgcn_s_sleep(4);
        }
        if (lane == 0)
          __hip_atomic_store(&goC, c + 1, __ATOMIC_RELAXED,
                             __HIP_MEMORY_SCOPE_WORKGROUP);
      } else {
        while (__hip_atomic_load(&goC, __ATOMIC_RELAXED,
                                 __HIP_MEMORY_SCOPE_WORKGROUP) < c + 1)
          __builtin_amdgcn_s_sleep(2);
      }
      __syncthreads();  // all waves past the chunk gate before tile loads
    }
    // ---- Phase A: tiled GEMM, gates for chunk c -> gl ----
    {
      float accq[4] = {0.f, 0.f, 0.f, 0.f};
      for (int k0 = 0; k0 < kin; k0 += 64) {
#pragma unroll
        for (int i = 0; i < 8; i++) {        // As: 64x64 = 4096, 8/thread
          int idx = tid + i * 512;
          int r = idx >> 6, kk = idx & 63;
          int k = k0 + kk;
          As[r][kk] = (k < kin)
              ? __hip_atomic_load(&Hin[(size_t)(t0 + r) * HPAD + k],
                                  __ATOMIC_RELAXED, __HIP_MEMORY_SCOPE_AGENT)
              : 0.f;
        }
#pragma unroll
        for (int i = 0; i < 4; i++) {        // Bs: 32x64 = 2048, 4/thread
          int idx = tid + i * 512;
          int r = idx >> 6, kk = idx & 63;
          int k = k0 + kk;
          int q = r >> 3, nb = blk * 8 + (r & 7);
          Bs[r][kk] = (k < kin) ? WihL[(size_t)(q * NN + nb) * kin + k] : 0.f;
        }
        __syncthreads();
#pragma unroll
        for (int kk = 0; kk < 64; kk++) {
          float av = As[ttA][kk];            // broadcast within 8-thread group
          accq[0] += av * Bs[w8][kk];        // rows (r+kk)%32 distinct: no conflict
          accq[1] += av * Bs[8 + w8][kk];
          accq[2] += av * Bs[16 + w8][kk];
          accq[3] += av * Bs[24 + w8][kk];
        }
        __syncthreads();
      }
#pragma unroll
      for (int q = 0; q < 4; q++)
        gl[ttA * 32 + q * 8 + w8] = accq[q] + pbA[q];
    }
    __syncthreads();  // gl visible to recurrence readers (needed at t==0)

    // ---- 64 recurrence steps ----
    for (int tt = 0; tt < TC; tt++) {
      int t = t0 + tt;
      if (t > 0) {
        if (wave == 0) {
          for (;;) {
            int ok = 1;
            if (lane < LB)
              ok &= (__hip_atomic_load(&fown[lane], __ATOMIC_RELAXED,
                                       __HIP_MEMORY_SCOPE_AGENT) >= t);
            if (lane < LB - 64)
              ok &= (__hip_atomic_load(&fown[64 + lane], __ATOMIC_RELAXED,
                                       __HIP_MEMORY_SCOPE_AGENT) >= t);
            if (__all(ok)) break;
            __builtin_amdgcn_s_sleep(2);
          }
          if (lane == 0)
            __hip_atomic_store(&go[tt], t, __ATOMIC_RELAXED,
                               __HIP_MEMORY_SCOPE_WORKGROUP);
        } else {
          while (__hip_atomic_load(&go[tt], __ATOMIC_RELAXED,
                                   __HIP_MEMORY_SCOPE_WORKGROUP) < t)
            __builtin_amdgcn_s_sleep(1);
        }
        // gather h[t-1]: 512 threads, 2 elements each (sc1: intra-dispatch)
        if (tid < NN)
          hs[tid] = __hip_atomic_load(&Hout[(size_t)(t - 1) * HPAD + tid],
                                      __ATOMIC_RELAXED, __HIP_MEMORY_SCOPE_AGENT);
        {
          int i2 = tid + 512;
          if (i2 < NN)
            hs[i2] = __hip_atomic_load(&Hout[(size_t)(t - 1) * HPAD + i2],
                                       __ATOMIC_RELAXED, __HIP_MEMORY_SCOPE_AGENT);
        }
        __syncthreads();
      }
      {
        float g0 = gl[tt * 32 + wave];
        float g1 = gl[tt * 32 + 8 + wave];
        float g2 = gl[tt * 32 + 16 + wave];
        float g3 = gl[tt * 32 + 24 + wave];
        if (t > 0) {
          float a0 = 0.f, a1 = 0.f, a2 = 0.f, a3 = 0.f;
#pragma unroll
          for (int it = 0; it < 16; it++) {
            float hv = hs[it * 64 + lane];
            a0 += wreg[0][it] * hv;
            a1 += wreg[1][it] * hv;
            a2 += wreg[2][it] * hv;
            a3 += wreg[3][it] * hv;
          }
#pragma unroll
          for (int o = 32; o; o >>= 1) {
            a0 += __shfl_xor(a0, o);
            a1 += __shfl_xor(a1, o);
            a2 += __shfl_xor(a2, o);
            a3 += __shfl_xor(a3, o);
          }
          g0 += a0; g1 += a1; g2 += a2; g3 += a3;
        }
        float ii = 1.f / (1.f + expf(-g0));
        float ff = 1.f / (1.f + expf(-g1));
        float gg = tanhf(g2);
        float oo = 1.f / (1.f + expf(-g3));
        creg = ff * creg + ii * gg;
        float h = oo * tanhf(creg);
        if (lane == 0)
          __hip_atomic_store(&Hout[(size_t)t * HPAD + n], h, __ATOMIC_RELAXED,
                             __HIP_MEMORY_SCOPE_AGENT);
      }
      asm volatile("s_waitcnt vmcnt(0)" ::: "memory");  // own h store acked
      __syncthreads();  // all 8 waves drained before publish
      if (tid == 0)
        __hip_atomic_store(&fown[blk], t + 1, __ATOMIC_RELAXED,
                           __HIP_MEMORY_SCOPE_AGENT);
    }
  }
}

// ---------------- epilogue ----------------
__global__ __launch_bounds__(256) void epilogue_out(
    const float* __restrict__ H7,   // [QQ, HPAD]
    const float* __restrict__ Wlin, const float* __restrict__ blin,
    const int* __restrict__ ccol, const float* __restrict__ Dnz,
    float* __restrict__ out,        // [QQ, NN]
    float* __restrict__ irbuf, float* __restrict__ mnirbuf) {
  int t = blockIdx.x, tid = threadIdx.x;
  int wave = tid >> 6, lane = tid & 63;
  __shared__ float hbuf[NN];
  __shared__ float smin[4], smax[4];
  __shared__ float bc[2];
  float lmin = 3.4e38f, lmax = -3.4e38f;
  for (int i = tid; i < NN; i += 256) {
    float v = H7[(size_t)t * HPAD + i];
    hbuf[i] = v;
    lmin = fminf(lmin, v); lmax = fmaxf(lmax, v);
  }
  lmin = wred_min(lmin); lmax = wred_max(lmax);
  if (lane == 0) { smin[wave] = lmin; smax[wave] = lmax; }
  __syncthreads();
  if (tid == 0) {
    bc[0] = fminf(fminf(smin[0], smin[1]), fminf(smin[2], smin[3]));
    bc[1] = fmaxf(fmaxf(smax[0], smax[1]), fmaxf(smax[2], smax[3]));
  }
  __syncthreads();
  float hmn = bc[0], hmx = bc[1];
  float clo = 3.4e38f, chi = -3.4e38f;
  if (tid < CCON) {
    float w = Wlin[tid], b = blin[tid];
    clo = b + fminf(w * hmn, w * hmx);
    chi = b + fmaxf(w * hmn, w * hmx);
  }
  clo = wred_min(clo); chi = wred_max(chi);
  __syncthreads();  // smin/smax reused below
  if (lane == 0) { smin[wave] = clo; smax[wave] = chi; }
  __syncthreads();
  if (tid == 0) {
    float mn = fminf(fminf(smin[0], smin[1]), fminf(smin[2], smin[3]));
    float mx = fmaxf(fmaxf(smax[0], smax[1]), fmaxf(smax[2], smax[3]));
    float ir = 1.f / (mx - mn);
    bc[0] = mn; bc[1] = ir;
    irbuf[t] = ir;
    mnirbuf[t] = mn * ir;
  }
  __syncthreads();
  float mn = bc[0], ir = bc[1];
  int cc = ccol[t];
  float wcc = Wlin[cc], bcc = blin[cc], d = Dnz[t];
  for (int n = tid; n < NN; n += 256) {
    float s = (hbuf[n] * wcc + bcc - mn) * ir;
    out[(size_t)t * NN + n] = fmaxf(0.25f, 1.f - expf(-10.f * (s - d)));
  }
}

__global__ void reduce_scalars(const float* __restrict__ ir,
                               const float* __restrict__ mnir,
                               float* __restrict__ scal) {
  int tid = threadIdx.x;  // 512
  int wave = tid >> 6, lane = tid & 63;
  __shared__ float s1[8], s2[8];
  float a = ir[tid], b = mnir[tid];
  a = wred_sum(a); b = wred_sum(b);
  if (lane == 0) { s1[wave] = a; s2[wave] = b; }
  __syncthreads();
  if (tid == 0) {
    float A = 0.f, B = 0.f;
    for (int i = 0; i < 8; i++) { A += s1[i]; B += s2[i]; }
    scal[0] = A; scal[1] = B;
  }
}

__global__ void accum_A(const float* __restrict__ H7,
                        const float* __restrict__ ir,
                        float* __restrict__ Avec) {
  int n = blockIdx.x * 256 + threadIdx.x;
  if (n < NN) {
    float acc = 0.f;
    for (int t = 0; t < QQ; t++) acc += H7[(size_t)t * HPAD + n] * ir[t];
    Avec[n] = acc;
  }
}

__global__ void skills_out(const float* __restrict__ Avec,
                           const float* __restrict__ Wlin,
                           const float* __restrict__ blin,
                           const float* __restrict__ scal,
                           float* __restrict__ out) {  // [NN, CCON]
  int idx = blockIdx.x * 256 + threadIdx.x;
  if (idx < NN * CCON) {
    int n = idx >> 7, c = idx & 127;
    out[idx] = (Wlin[c] * Avec[n] + blin[c] * scal[0] - scal[1]) * (1.f / (float)QQ);
  }
}

extern "C" void kernel_launch(void* const* d_in, const int* in_sizes, int n_in,
                              void* d_out, int out_size, void* d_ws, size_t ws_size,
                              hipStream_t stream) {
  const float* inputs = (const float*)d_in[0];
  const int*   ccol   = (const int*)d_in[1];
  const float* W_inp  = (const float*)d_in[2];
  const float* b_inp  = (const float*)d_in[3];
  const float* W_ih0  = (const float*)d_in[4];
  const float* W_hh0  = (const float*)d_in[5];
  const float* b_ih0  = (const float*)d_in[6];
  const float* b_hh0  = (const float*)d_in[7];
  const float* W_ih   = (const float*)d_in[8];   // [7, 4000, 1000]
  const float* W_hh   = (const float*)d_in[9];   // [7, 4000, 1000]
  const float* b_ih   = (const float*)d_in[10];  // [7, 4000]
  const float* b_hh   = (const float*)d_in[11];  // [7, 4000]
  const float* W_lin  = (const float*)d_in[12];  // [128]
  const float* b_lin  = (const float*)d_in[13];  // [128]
  const float* D_nz   = (const float*)d_in[14];  // [512]

  float* ws = (float*)d_ws;
  float* X    = ws;                           // [512,1024] padded rows
  float* H    = X + (size_t)QQ * HPAD;        // [8][512][1024]
  float* irb  = H + (size_t)LAYERS * QQ * HPAD; // [512]
  float* mnir = irb + QQ;                     // [512]
  float* Avec = mnir + QQ;                    // [1024]
  float* scal = Avec + 1024;                  // [2] (+pad)
  int*   flags = (int*)(scal + 16);           // [8*128] stamped flags

  float* out_main   = (float*)d_out;            // [512,1000]
  float* out_skills = (float*)d_out + QQ * NN;  // [1000,128]

  // Zero all layer flags (captured in graph; re-zeroed every replay).
  hipMemsetAsync(flags, 0, LAYERS * 128 * sizeof(int), stream);

  // X = inputs @ W_inp^T + b_inp   (M=512, K=1000, R=1024, ldc=HPAD)
  gemm_nt<<<dim3(HPAD / 64, QQ / 64), 256, 0, stream>>>(
      inputs, W_inp, b_inp, X, QQ, NN, HPAD, NN, HPAD);

  // Single persistent dataflow pipeline: all 8 layers, chunk-granular.
  PipeArgs pa;
  pa.X = X; pa.Wih0 = W_ih0; pa.Whh0 = W_hh0; pa.bih0 = b_ih0; pa.bhh0 = b_hh0;
  pa.Wih = W_ih; pa.Whh = W_hh; pa.bih = b_ih; pa.bhh = b_hh;
  pa.H = H; pa.flags = flags;
  lstm_pipe<<<LAYERS * LB, 512, 0, stream>>>(pa);

  float* H7 = H + (size_t)7 * QQ * HPAD;
  epilogue_out<<<QQ, 256, 0, stream>>>(H7, W_lin, b_lin, ccol, D_nz,
                                       out_main, irb, mnir);
  reduce_scalars<<<1, 512, 0, stream>>>(irb, mnir, scal);
  accum_A<<<4, 256, 0, stream>>>(H7, irb, Avec);
  skills_out<<<(NN * CCON) / 256, 256, 0, stream>>>(Avec, W_lin, b_lin, scal,
                                                    out_skills);
}

// Round 17
// 9365.033 us; speedup vs baseline: 1.4154x; 1.4154x over previous
//
#include <hip/hip_runtime.h>
#include <math.h>

#define QQ 512
#define NN 1000
#define HHID 1024
#define HPAD 1024   // padded row stride for h trajectories (X uses 1024 too)
#define CCON 128
#define G4 4000
#define LAYERS 8
#define TC 64                       // timestep chunk
#define CHUNKS (QQ / TC)            // 8
#define CONC 8      // pairs/stage: 504x1024-thr blocks pack 2/CU (r7 proof);
                    // LDS 55.8KBx2=111.6<=160KB, VGPR 60<=64 (8 waves/SIMD)
#define LBLK 63     // blocks per pair, 1024 thr, 1 neuron/wave

__device__ inline float wred_min(float v){ for(int o=32;o;o>>=1) v=fminf(v,__shfl_xor(v,o)); return v; }
__device__ inline float wred_max(float v){ for(int o=32;o;o>>=1) v=fmaxf(v,__shfl_xor(v,o)); return v; }
__device__ inline float wred_sum(float v){ for(int o=32;o;o>>=1) v+=__shfl_xor(v,o); return v; }

// ---------------- generic NT GEMM (X prologue only) ----------------
__global__ __launch_bounds__(256) void gemm_nt(
    const float* __restrict__ A, const float* __restrict__ B,
    const float* __restrict__ bias1,
    float* __restrict__ C, int M, int K, int R, int lda, int ldc) {
  __shared__ float As[16][65];
  __shared__ float Bs[16][65];
  int tid = threadIdx.x;
  int tx = tid & 15, ty = tid >> 4;
  int m0 = blockIdx.y * 64, r0 = blockIdx.x * 64;
  float acc[4][4] = {};
  for (int k0 = 0; k0 < K; k0 += 16) {
#pragma unroll
    for (int i = 0; i < 4; i++) {
      int idx = tid + 256 * i;
      int ml = idx >> 4, kl = idx & 15;
      int m = m0 + ml, k = k0 + kl;
      As[kl][ml] = (m < M && k < K) ? A[(size_t)m * lda + k] : 0.f;
      int r = r0 + ml;
      Bs[kl][ml] = (r < R && k < K) ? B[(size_t)r * K + k] : 0.f;
    }
    __syncthreads();
#pragma unroll
    for (int kk = 0; kk < 16; kk++) {
      float a[4], b[4];
#pragma unroll
      for (int i = 0; i < 4; i++) a[i] = As[kk][ty * 4 + i];
#pragma unroll
      for (int j = 0; j < 4; j++) b[j] = Bs[kk][tx * 4 + j];
#pragma unroll
      for (int i = 0; i < 4; i++)
#pragma unroll
        for (int j = 0; j < 4; j++) acc[i][j] += a[i] * b[j];
    }
    __syncthreads();
  }
#pragma unroll
  for (int i = 0; i < 4; i++) {
    int m = m0 + ty * 4 + i;
    if (m >= M) continue;
#pragma unroll
    for (int j = 0; j < 4; j++) {
      int r = r0 + tx * 4 + j;
      if (r >= R) continue;
      float v = acc[i][j];
      if (bias1) v += bias1[r];
      C[(size_t)m * ldc + r] = v;
    }
  }
}

// ---------------- fused per-stage recurrence (gates + TC steps) ----------
// Round-15 proven body. Phase A: LDS-tiled 64x64xkin GEMM for input gates
// (W_ih read once, no register preload). Phase B: W_hh in 64 pinned VGPRs,
// wave-0 flag poll + LDS go release, relaxed sc1 atomics, NO fences (agent
// acquire fence = buffer_inv = full L2 invalidate, round-3 lesson).
struct RPair { const float* Hin; const float* Wih; const float* b1;
               const float* b2; const float* Whh; float* Hout; int* flag;
               float* Call; int t0; int kin; };
struct RArgs { RPair p[CONC]; };

__global__ __launch_bounds__(1024, 4) void lstm_stage(RArgs args) {
  RPair rp = args.p[blockIdx.y];
  __shared__ __align__(16) float As[64][68];  // 68: float4-aligned rows
  __shared__ __align__(16) float Bs[64][68];
  __shared__ float gl[TC * 64];   // gates: gl[tt*64 + q*16 + w]
  __shared__ float hs[1024];      // Phase B h broadcast
  __shared__ int go[TC];
  int tid = threadIdx.x;
  int wave = tid >> 6, lane = tid & 63;
  int n = blockIdx.x * 16 + wave;
  bool active = (n < NN);
  int kin = rp.kin;               // 1024 for layer 0 (X), 1000 otherwise
  int t0 = rp.t0;

  if (tid >= NN) hs[tid] = 0.f;   // zero pad once
  if (tid < TC) go[tid] = 0;

  // ---- Phase A: tiled GEMM for input-side gates ----
  {
    int tt = tid >> 4;            // 0..63 timestep within chunk
    int w16 = tid & 15;           // neuron within block
    int nn = blockIdx.x * 16 + w16;
    float accq[4] = {0.f, 0.f, 0.f, 0.f};
    float pbq[4];
#pragma unroll
    for (int q = 0; q < 4; q++)
      pbq[q] = (nn < NN) ? rp.b1[q * NN + nn] + rp.b2[q * NN + nn] : 0.f;
    for (int k0 = 0; k0 < kin; k0 += 64) {
#pragma unroll
      for (int i = 0; i < 4; i++) {
        int idx = tid + i * 1024;
        int r = idx >> 6, kk = idx & 63;
        int k = k0 + kk;
        // Hin rows are prev-dispatch data: plain loads legal
        As[r][kk] = (k < kin) ? rp.Hin[(size_t)(t0 + r) * HPAD + k] : 0.f;
        int q = r >> 4, nb = blockIdx.x * 16 + (r & 15);
        Bs[r][kk] = (nb < NN && k < kin)
                        ? rp.Wih[(size_t)(q * NN + nb) * kin + k] : 0.f;
      }
      __syncthreads();
#pragma unroll
      for (int kk = 0; kk < 64; kk += 4) {
        float4 av = *(const float4*)&As[tt][kk];
#pragma unroll
        for (int q = 0; q < 4; q++) {
          float4 bv = *(const float4*)&Bs[q * 16 + w16][kk];
          accq[q] += av.x * bv.x + av.y * bv.y + av.z * bv.z + av.w * bv.w;
        }
      }
      __syncthreads();
    }
#pragma unroll
    for (int q = 0; q < 4; q++)
      gl[tt * 64 + q * 16 + w16] = accq[q] + pbq[q];
  }

  // ---- Phase B: W_hh preload (64 pinned VGPRs) + recurrence ----
  float wreg[4][16];
  if (active) {
#pragma unroll
    for (int q = 0; q < 4; q++) {
      const float* wr = rp.Whh + (size_t)(q * NN + n) * NN;
#pragma unroll
      for (int it = 0; it < 16; it++) {
        int k = it * 64 + lane;
        wreg[q][it] = (k < NN) ? wr[k] : 0.f;
      }
    }
  } else {
#pragma unroll
    for (int q = 0; q < 4; q++)
#pragma unroll
      for (int it = 0; it < 16; it++) wreg[q][it] = 0.f;
  }
#pragma unroll
  for (int q = 0; q < 4; q++)
#pragma unroll
    for (int it = 0; it < 16; it++)
      asm volatile("" : "+v"(wreg[q][it]));  // keep register-resident

  __syncthreads();  // gl complete, go/hs-pad init visible

  float creg = 0.f;
  if (t0 > 0 && active) creg = rp.Call[n];  // prev-dispatch data, plain load

  for (int tt = 0; tt < TC; tt++) {
    int t = t0 + tt;
    if (t > 0) {
      if (wave == 0) {
        for (;;) {
          int v = t;
          if (lane < LBLK)
            v = __hip_atomic_load(&rp.flag[lane], __ATOMIC_RELAXED,
                                  __HIP_MEMORY_SCOPE_AGENT);
          if (__all(v >= t)) break;
          __builtin_amdgcn_s_sleep(2);
        }
        if (lane == 0)
          __hip_atomic_store(&go[tt], 1, __ATOMIC_RELAXED,
                             __HIP_MEMORY_SCOPE_WORKGROUP);
      } else {
        while (__hip_atomic_load(&go[tt], __ATOMIC_RELAXED,
                                 __HIP_MEMORY_SCOPE_WORKGROUP) == 0)
          __builtin_amdgcn_s_sleep(1);
      }
      if (tid < NN)  // intra-dispatch cross-block: sc1 required
        hs[tid] = __hip_atomic_load(&rp.Hout[(size_t)(t - 1) * HPAD + tid],
                                    __ATOMIC_RELAXED, __HIP_MEMORY_SCOPE_AGENT);
      __syncthreads();
    }
    if (active) {
      float g0 = gl[tt * 64 + wave];
      float g1 = gl[tt * 64 + 16 + wave];
      float g2 = gl[tt * 64 + 32 + wave];
      float g3 = gl[tt * 64 + 48 + wave];
      if (t > 0) {
        float a0 = 0.f, a1 = 0.f, a2 = 0.f, a3 = 0.f;
#pragma unroll
        for (int it = 0; it < 16; it++) {
          float hv = hs[it * 64 + lane];
          a0 += wreg[0][it] * hv;
          a1 += wreg[1][it] * hv;
          a2 += wreg[2][it] * hv;
          a3 += wreg[3][it] * hv;
        }
#pragma unroll
        for (int o = 32; o; o >>= 1) {
          a0 += __shfl_xor(a0, o);
          a1 += __shfl_xor(a1, o);
          a2 += __shfl_xor(a2, o);
          a3 += __shfl_xor(a3, o);
        }
        g0 += a0; g1 += a1; g2 += a2; g3 += a3;
      }
      float ii = 1.f / (1.f + expf(-g0));
      float ff = 1.f / (1.f + expf(-g1));
      float gg = tanhf(g2);
      float oo = 1.f / (1.f + expf(-g3));
      creg = ff * creg + ii * gg;
      float h = oo * tanhf(creg);
      if (lane == 0)
        __hip_atomic_store(&rp.Hout[(size_t)t * HPAD + n], h, __ATOMIC_RELAXED,
                           __HIP_MEMORY_SCOPE_AGENT);
    }
    asm volatile("s_waitcnt vmcnt(0)" ::: "memory");  // own h store acked
    __syncthreads();  // all waves' stores drained before publish
    if (tid == 0)
      __hip_atomic_store(&rp.flag[blockIdx.x], t + 1, __ATOMIC_RELAXED,
                         __HIP_MEMORY_SCOPE_AGENT);
  }
  if (active && lane == 0)
    __hip_atomic_store(&rp.Call[n], creg, __ATOMIC_RELAXED,
                       __HIP_MEMORY_SCOPE_AGENT);
}

// ---------------- epilogue ----------------
__global__ __launch_bounds__(256) void epilogue_out(
    const float* __restrict__ H7,   // [QQ, HPAD]
    const float* __restrict__ Wlin, const float* __restrict__ blin,
    const int* __restrict__ ccol, const float* __restrict__ Dnz,
    float* __restrict__ out,        // [QQ, NN]
    float* __restrict__ irbuf, float* __restrict__ mnirbuf) {
  int t = blockIdx.x, tid = threadIdx.x;
  int wave = tid >> 6, lane = tid & 63;
  __shared__ float hbuf[NN];
  __shared__ float smin[4], smax[4];
  __shared__ float bc[2];
  float lmin = 3.4e38f, lmax = -3.4e38f;
  for (int i = tid; i < NN; i += 256) {
    float v = H7[(size_t)t * HPAD + i];
    hbuf[i] = v;
    lmin = fminf(lmin, v); lmax = fmaxf(lmax, v);
  }
  lmin = wred_min(lmin); lmax = wred_max(lmax);
  if (lane == 0) { smin[wave] = lmin; smax[wave] = lmax; }
  __syncthreads();
  if (tid == 0) {
    bc[0] = fminf(fminf(smin[0], smin[1]), fminf(smin[2], smin[3]));
    bc[1] = fmaxf(fmaxf(smax[0], smax[1]), fmaxf(smax[2], smax[3]));
  }
  __syncthreads();
  float hmn = bc[0], hmx = bc[1];
  float clo = 3.4e38f, chi = -3.4e38f;
  if (tid < CCON) {
    float w = Wlin[tid], b = blin[tid];
    clo = b + fminf(w * hmn, w * hmx);
    chi = b + fmaxf(w * hmn, w * hmx);
  }
  clo = wred_min(clo); chi = wred_max(chi);
  __syncthreads();  // smin/smax reused below
  if (lane == 0) { smin[wave] = clo; smax[wave] = chi; }
  __syncthreads();
  if (tid == 0) {
    float mn = fminf(fminf(smin[0], smin[1]), fminf(smin[2], smin[3]));
    float mx = fmaxf(fmaxf(smax[0], smax[1]), fmaxf(smax[2], smax[3]));
    float ir = 1.f / (mx - mn);
    bc[0] = mn; bc[1] = ir;
    irbuf[t] = ir;
    mnirbuf[t] = mn * ir;
  }
  __syncthreads();
  float mn = bc[0], ir = bc[1];
  int cc = ccol[t];
  float wcc = Wlin[cc], bcc = blin[cc], d = Dnz[t];
  for (int n = tid; n < NN; n += 256) {
    float s = (hbuf[n] * wcc + bcc - mn) * ir;
    out[(size_t)t * NN + n] = fmaxf(0.25f, 1.f - expf(-10.f * (s - d)));
  }
}

__global__ void reduce_scalars(const float* __restrict__ ir,
                               const float* __restrict__ mnir,
                               float* __restrict__ scal) {
  int tid = threadIdx.x;  // 512
  int wave = tid >> 6, lane = tid & 63;
  __shared__ float s1[8], s2[8];
  float a = ir[tid], b = mnir[tid];
  a = wred_sum(a); b = wred_sum(b);
  if (lane == 0) { s1[wave] = a; s2[wave] = b; }
  __syncthreads();
  if (tid == 0) {
    float A = 0.f, B = 0.f;
    for (int i = 0; i < 8; i++) { A += s1[i]; B += s2[i]; }
    scal[0] = A; scal[1] = B;
  }
}

__global__ void accum_A(const float* __restrict__ H7,
                        const float* __restrict__ ir,
                        float* __restrict__ Avec) {
  int n = blockIdx.x * 256 + threadIdx.x;
  if (n < NN) {
    float acc = 0.f;
    for (int t = 0; t < QQ; t++) acc += H7[(size_t)t * HPAD + n] * ir[t];
    Avec[n] = acc;
  }
}

__global__ void skills_out(const float* __restrict__ Avec,
                           const float* __restrict__ Wlin,
                           const float* __restrict__ blin,
                           const float* __restrict__ scal,
                           float* __restrict__ out) {  // [NN, CCON]
  int idx = blockIdx.x * 256 + threadIdx.x;
  if (idx < NN * CCON) {
    int n = idx >> 7, c = idx & 127;
    out[idx] = (Wlin[c] * Avec[n] + blin[c] * scal[0] - scal[1]) * (1.f / (float)QQ);
  }
}

extern "C" void kernel_launch(void* const* d_in, const int* in_sizes, int n_in,
                              void* d_out, int out_size, void* d_ws, size_t ws_size,
                              hipStream_t stream) {
  const float* inputs = (const float*)d_in[0];
  const int*   ccol   = (const int*)d_in[1];
  const float* W_inp  = (const float*)d_in[2];
  const float* b_inp  = (const float*)d_in[3];
  const float* W_ih0  = (const float*)d_in[4];
  const float* W_hh0  = (const float*)d_in[5];
  const float* b_ih0  = (const float*)d_in[6];
  const float* b_hh0  = (const float*)d_in[7];
  const float* W_ih   = (const float*)d_in[8];   // [7, 4000, 1000]
  const float* W_hh   = (const float*)d_in[9];   // [7, 4000, 1000]
  const float* b_ih   = (const float*)d_in[10];  // [7, 4000]
  const float* b_hh   = (const float*)d_in[11];  // [7, 4000]
  const float* W_lin  = (const float*)d_in[12];  // [128]
  const float* b_lin  = (const float*)d_in[13];  // [128]
  const float* D_nz   = (const float*)d_in[14];  // [512]

  float* ws = (float*)d_ws;
  float* X    = ws;                           // [512,1024] padded rows
  float* H    = X + (size_t)QQ * HPAD;        // [8][512][1024]
  float* Call = H + (size_t)LAYERS * QQ * HPAD; // [8][1024]
  float* irb  = Call + LAYERS * HPAD;         // [512]
  float* mnir = irb + QQ;                     // [512]
  float* Avec = mnir + QQ;                    // [1024]
  float* scal = Avec + 1024;                  // [2] (+pad)
  int*   flags = (int*)(scal + 16);           // [8*64] stamped flags

  float* out_main   = (float*)d_out;            // [512,1000]
  float* out_skills = (float*)d_out + QQ * NN;  // [1000,128]

  // Zero all layer flags (captured in graph; re-zeroed every replay).
  hipMemsetAsync(flags, 0, LAYERS * 64 * sizeof(int), stream);

  // X = inputs @ W_inp^T + b_inp   (M=512, K=1000, R=1024, ldc=HPAD)
  gemm_nt<<<dim3(HPAD / 64, QQ / 64), 256, 0, stream>>>(
      inputs, W_inp, b_inp, X, QQ, NN, HPAD, NN, HPAD);

  // List-scheduled wavefront, capped at CONC=8 pairs/stage: the full
  // dependence diagonal fits in one stage -> 15 stages (was 19 with CONC=4).
  // Worst case (only 4 pairs resident): np>4 stages split into 2 occupancy
  // rounds = same 19 rounds as before (neutral).
  bool donep[LAYERS][CHUNKS] = {};
  int remaining = LAYERS * CHUNKS;
  while (remaining > 0) {
    int pl[CONC], pcid[CONC];
    bool sel[LAYERS][CHUNKS] = {};
    int np = 0;
    for (int pick = 0; pick < CONC; pick++) {
      int bl = -1, bc = -1, bkey = 1 << 30;
      for (int l = 0; l < LAYERS; l++)
        for (int c = 0; c < CHUNKS; c++) {
          if (donep[l][c] || sel[l][c]) continue;
          if (l > 0 && !donep[l - 1][c]) continue;
          if (c > 0 && !donep[l][c - 1]) continue;
          int key = (l + c) * 16 + (LAYERS - 1 - l);
          if (key < bkey) { bkey = key; bl = l; bc = c; }
        }
      if (bl < 0) break;
      sel[bl][bc] = true; pl[np] = bl; pcid[np] = bc; np++;
    }
    RArgs ra;
    for (int i = 0; i < np; i++) {
      int l = pl[i], c = pcid[i];
      RPair& r = ra.p[i];
      if (l == 0) {
        r.Hin = X; r.Wih = W_ih0; r.b1 = b_ih0; r.b2 = b_hh0;
        r.Whh = W_hh0; r.kin = HHID;
      } else {
        r.Hin = H + (size_t)(l - 1) * QQ * HPAD;
        r.Wih = W_ih + (size_t)(l - 1) * G4 * NN;
        r.b1 = b_ih + (size_t)(l - 1) * G4;
        r.b2 = b_hh + (size_t)(l - 1) * G4;
        r.Whh = W_hh + (size_t)(l - 1) * G4 * NN;
        r.kin = NN;
      }
      r.Hout = H + (size_t)l * QQ * HPAD;
      r.flag = flags + l * 64;
      r.Call = Call + l * HPAD;
      r.t0 = c * TC;
    }
    for (int i = np; i < CONC; i++) ra.p[i] = ra.p[0];
    lstm_stage<<<dim3(LBLK, np), 1024, 0, stream>>>(ra);
    for (int i = 0; i < np; i++) donep[pl[i]][pcid[i]] = true;
    remaining -= np;
  }

  float* H7 = H + (size_t)7 * QQ * HPAD;
  epilogue_out<<<QQ, 256, 0, stream>>>(H7, W_lin, b_lin, ccol, D_nz,
                                       out_main, irb, mnir);
  reduce_scalars<<<1, 512, 0, stream>>>(irb, mnir, scal);
  accum_A<<<4, 256, 0, stream>>>(H7, irb, Avec);
  skills_out<<<(NN * CCON) / 256, 256, 0, stream>>>(Avec, W_lin, b_lin, scal,
                                                    out_skills);
}

// Round 18
// 9352.875 us; speedup vs baseline: 1.4172x; 1.0013x over previous
//
#include <hip/hip_runtime.h>
#include <math.h>

#define QQ 512
#define NN 1000
#define HHID 1024
#define HPAD 1024   // padded row stride for h trajectories (X uses 1024 too)
#define CCON 128
#define G4 4000
#define LAYERS 8
#define TC 64                       // timestep chunk
#define CHUNKS (QQ / TC)            // 8
#define LBLK 63                     // blocks per pair, 1024 thr, 1 n/wave
#define NPAIRS (LAYERS * CHUNKS)    // 64

__device__ inline float wred_min(float v){ for(int o=32;o;o>>=1) v=fminf(v,__shfl_xor(v,o)); return v; }
__device__ inline float wred_max(float v){ for(int o=32;o;o>>=1) v=fmaxf(v,__shfl_xor(v,o)); return v; }
__device__ inline float wred_sum(float v){ for(int o=32;o;o>>=1) v+=__shfl_xor(v,o); return v; }

// ---------------- generic NT GEMM (X prologue only) ----------------
__global__ __launch_bounds__(256) void gemm_nt(
    const float* __restrict__ A, const float* __restrict__ B,
    const float* __restrict__ bias1,
    float* __restrict__ C, int M, int K, int R, int lda, int ldc) {
  __shared__ float As[16][65];
  __shared__ float Bs[16][65];
  int tid = threadIdx.x;
  int tx = tid & 15, ty = tid >> 4;
  int m0 = blockIdx.y * 64, r0 = blockIdx.x * 64;
  float acc[4][4] = {};
  for (int k0 = 0; k0 < K; k0 += 16) {
#pragma unroll
    for (int i = 0; i < 4; i++) {
      int idx = tid + 256 * i;
      int ml = idx >> 4, kl = idx & 15;
      int m = m0 + ml, k = k0 + kl;
      As[kl][ml] = (m < M && k < K) ? A[(size_t)m * lda + k] : 0.f;
      int r = r0 + ml;
      Bs[kl][ml] = (r < R && k < K) ? B[(size_t)r * K + k] : 0.f;
    }
    __syncthreads();
#pragma unroll
    for (int kk = 0; kk < 16; kk++) {
      float a[4], b[4];
#pragma unroll
      for (int i = 0; i < 4; i++) a[i] = As[kk][ty * 4 + i];
#pragma unroll
      for (int j = 0; j < 4; j++) b[j] = Bs[kk][tx * 4 + j];
#pragma unroll
      for (int i = 0; i < 4; i++)
#pragma unroll
        for (int j = 0; j < 4; j++) acc[i][j] += a[i] * b[j];
    }
    __syncthreads();
  }
#pragma unroll
  for (int i = 0; i < 4; i++) {
    int m = m0 + ty * 4 + i;
    if (m >= M) continue;
#pragma unroll
    for (int j = 0; j < 4; j++) {
      int r = r0 + tx * 4 + j;
      if (r >= R) continue;
      float v = acc[i][j];
      if (bias1) v += bias1[r];
      C[(size_t)m * ldc + r] = v;
    }
  }
}

// ------------- self-timed mega-launch: all 64 (layer,chunk) pairs --------
// Grid = 64 pairs x 63 blocks, blockIdx in TOPOLOGICAL pair order (diagonal
// s=l+c asc, deeper layer first). In-order dispatch + prefix-residency =>
// every resident block's dependencies are earlier blockIdx (done or
// resident) -> no deadlock; ~4 pairs resident (1 blk/CU) self-schedule.
// Readiness via stamped per-layer flags only:
//   gateA (l>0): fprev >= t0+64  -> Phase A input chunk complete
//   gateB (t0>0): fown >= t0     -> prev chunk of own layer done (h & Call)
// Call is stored INSIDE the last step (drained by the same vmcnt+barrier
// before the final flag publish) so fown >= t0 also covers Call.
// All intra-dispatch cross-block data via relaxed sc1 agent atomics; NO
// fences (agent acquire fence = buffer_inv = full L2 inval, round-3 lesson).
// W_hh loads issued+pinned BEFORE Phase A: latency hides under the GEMM.
struct WaveArgs {
  const float* X;
  const float* Wih0; const float* Whh0; const float* bih0; const float* bhh0;
  const float* Wih7; const float* Whh7; const float* bih7; const float* bhh7;
  float* H; float* Call; int* flags;
  int pl[NPAIRS]; int pc[NPAIRS];
};

__global__ __launch_bounds__(1024, 4) void lstm_wave(WaveArgs a) {
  int pidx = blockIdx.x / LBLK;
  int blkid = blockIdx.x - pidx * LBLK;
  int l = a.pl[pidx], c = a.pc[pidx];
  int t0 = c * TC;
  int kin = (l == 0) ? HHID : NN;
  const float* Wih = (l == 0) ? a.Wih0 : a.Wih7 + (size_t)(l - 1) * G4 * NN;
  const float* Whh = (l == 0) ? a.Whh0 : a.Whh7 + (size_t)(l - 1) * G4 * NN;
  const float* b1  = (l == 0) ? a.bih0 : a.bih7 + (size_t)(l - 1) * G4;
  const float* b2  = (l == 0) ? a.bhh0 : a.bhh7 + (size_t)(l - 1) * G4;
  const float* Hin = (l == 0) ? a.X : a.H + (size_t)(l - 1) * QQ * HPAD;
  float* Hout = a.H + (size_t)l * QQ * HPAD;
  int* fown = a.flags + l * 64;
  const int* fprev = a.flags + (l - 1) * 64;
  float* CallL = a.Call + l * HPAD;

  __shared__ __align__(16) float As[64][68];
  __shared__ __align__(16) float Bs[64][68];
  __shared__ float gl[TC * 64];   // gates: gl[tt*64 + q*16 + w]
  __shared__ float hs[1024];
  __shared__ int go[TC];
  __shared__ int goA;
  int tid = threadIdx.x;
  int wave = tid >> 6, lane = tid & 63;
  int n = blkid * 16 + wave;
  bool active = (n < NN);

  if (tid >= NN) hs[tid] = 0.f;
  if (tid < TC) go[tid] = 0;
  if (tid == 0) goA = 0;

  // ---- W_hh preload issued + pinned NOW (hides under Phase A) ----
  float wreg[4][16];
  if (active) {
#pragma unroll
    for (int q = 0; q < 4; q++) {
      const float* wr = Whh + (size_t)(q * NN + n) * NN;
#pragma unroll
      for (int it = 0; it < 16; it++) {
        int k = it * 64 + lane;
        wreg[q][it] = (k < NN) ? wr[k] : 0.f;
      }
    }
  } else {
#pragma unroll
    for (int q = 0; q < 4; q++)
#pragma unroll
      for (int it = 0; it < 16; it++) wreg[q][it] = 0.f;
  }
#pragma unroll
  for (int q = 0; q < 4; q++)
#pragma unroll
    for (int it = 0; it < 16; it++)
      asm volatile("" : "+v"(wreg[q][it]));  // materialize early, keep live

  __syncthreads();  // go/goA/hs-pad init visible

  // ---- gateA: prev layer finished chunk c ----
  if (l > 0) {
    int need = t0 + TC;
    if (wave == 0) {
      for (;;) {
        int v = need;
        if (lane < LBLK)
          v = __hip_atomic_load(&fprev[lane], __ATOMIC_RELAXED,
                                __HIP_MEMORY_SCOPE_AGENT);
        if (__all(v >= need)) break;
        __builtin_amdgcn_s_sleep(4);
      }
      if (lane == 0)
        __hip_atomic_store(&goA, 1, __ATOMIC_RELAXED,
                           __HIP_MEMORY_SCOPE_WORKGROUP);
    } else {
      while (__hip_atomic_load(&goA, __ATOMIC_RELAXED,
                               __HIP_MEMORY_SCOPE_WORKGROUP) < 1)
        __builtin_amdgcn_s_sleep(4);
    }
  }

  // ---- Phase A: tiled GEMM for input-side gates (Hin via sc1) ----
  {
    int tt = tid >> 4;            // 0..63 timestep within chunk
    int w16 = tid & 15;           // neuron within block
    int nn = blkid * 16 + w16;
    float accq[4] = {0.f, 0.f, 0.f, 0.f};
    float pbq[4];
#pragma unroll
    for (int q = 0; q < 4; q++)
      pbq[q] = (nn < NN) ? b1[q * NN + nn] + b2[q * NN + nn] : 0.f;
    for (int k0 = 0; k0 < kin; k0 += 64) {
#pragma unroll
      for (int i = 0; i < 4; i++) {
        int idx = tid + i * 1024;
        int r = idx >> 6, kk = idx & 63;
        int k = k0 + kk;
        As[r][kk] = (k < kin)
            ? __hip_atomic_load(&Hin[(size_t)(t0 + r) * HPAD + k],
                                __ATOMIC_RELAXED, __HIP_MEMORY_SCOPE_AGENT)
            : 0.f;
        int q = r >> 4, nb = blkid * 16 + (r & 15);
        Bs[r][kk] = (nb < NN && k < kin)
                        ? Wih[(size_t)(q * NN + nb) * kin + k] : 0.f;
      }
      __syncthreads();
#pragma unroll
      for (int kk = 0; kk < 64; kk += 4) {
        float4 av = *(const float4*)&As[tt][kk];
#pragma unroll
        for (int q = 0; q < 4; q++) {
          float4 bv = *(const float4*)&Bs[q * 16 + w16][kk];
          accq[q] += av.x * bv.x + av.y * bv.y + av.z * bv.z + av.w * bv.w;
        }
      }
      __syncthreads();
    }
#pragma unroll
    for (int q = 0; q < 4; q++)
      gl[tt * 64 + q * 16 + w16] = accq[q] + pbq[q];
  }

  // ---- gateB: own layer finished chunk c-1 (covers h[t0-1] AND Call) ----
  if (t0 > 0) {
    if (wave == 0) {
      for (;;) {
        int v = t0;
        if (lane < LBLK)
          v = __hip_atomic_load(&fown[lane], __ATOMIC_RELAXED,
                                __HIP_MEMORY_SCOPE_AGENT);
        if (__all(v >= t0)) break;
        __builtin_amdgcn_s_sleep(4);
      }
      if (lane == 0)
        __hip_atomic_store(&goA, 2, __ATOMIC_RELAXED,
                           __HIP_MEMORY_SCOPE_WORKGROUP);
    } else {
      while (__hip_atomic_load(&goA, __ATOMIC_RELAXED,
                               __HIP_MEMORY_SCOPE_WORKGROUP) < 2)
        __builtin_amdgcn_s_sleep(4);
    }
  }
  float creg = 0.f;
  if (t0 > 0 && active)
    creg = __hip_atomic_load(&CallL[n], __ATOMIC_RELAXED,
                             __HIP_MEMORY_SCOPE_AGENT);
  __syncthreads();  // gl complete before recurrence reads

  // ---- 64 recurrence steps ----
  for (int tt = 0; tt < TC; tt++) {
    int t = t0 + tt;
    if (tt > 0) {  // tt==0 readiness came from gateB
      if (wave == 0) {
        for (;;) {
          int v = t;
          if (lane < LBLK)
            v = __hip_atomic_load(&fown[lane], __ATOMIC_RELAXED,
                                  __HIP_MEMORY_SCOPE_AGENT);
          if (__all(v >= t)) break;
          __builtin_amdgcn_s_sleep(2);
        }
        if (lane == 0)
          __hip_atomic_store(&go[tt], 1, __ATOMIC_RELAXED,
                             __HIP_MEMORY_SCOPE_WORKGROUP);
      } else {
        while (__hip_atomic_load(&go[tt], __ATOMIC_RELAXED,
                                 __HIP_MEMORY_SCOPE_WORKGROUP) == 0)
          __builtin_amdgcn_s_sleep(1);
      }
    }
    if (t > 0) {
      if (tid < NN)
        hs[tid] = __hip_atomic_load(&Hout[(size_t)(t - 1) * HPAD + tid],
                                    __ATOMIC_RELAXED, __HIP_MEMORY_SCOPE_AGENT);
      __syncthreads();
    }
    if (active) {
      float g0 = gl[tt * 64 + wave];
      float g1 = gl[tt * 64 + 16 + wave];
      float g2 = gl[tt * 64 + 32 + wave];
      float g3 = gl[tt * 64 + 48 + wave];
      if (t > 0) {
        float a0 = 0.f, a1 = 0.f, a2 = 0.f, a3 = 0.f;
#pragma unroll
        for (int it = 0; it < 16; it++) {
          float hv = hs[it * 64 + lane];
          a0 += wreg[0][it] * hv;
          a1 += wreg[1][it] * hv;
          a2 += wreg[2][it] * hv;
          a3 += wreg[3][it] * hv;
        }
#pragma unroll
        for (int o = 32; o; o >>= 1) {
          a0 += __shfl_xor(a0, o);
          a1 += __shfl_xor(a1, o);
          a2 += __shfl_xor(a2, o);
          a3 += __shfl_xor(a3, o);
        }
        g0 += a0; g1 += a1; g2 += a2; g3 += a3;
      }
      float ii = 1.f / (1.f + expf(-g0));
      float ff = 1.f / (1.f + expf(-g1));
      float gg = tanhf(g2);
      float oo = 1.f / (1.f + expf(-g3));
      creg = ff * creg + ii * gg;
      float h = oo * tanhf(creg);
      if (lane == 0) {
        __hip_atomic_store(&Hout[(size_t)t * HPAD + n], h, __ATOMIC_RELAXED,
                           __HIP_MEMORY_SCOPE_AGENT);
        if (tt == TC - 1)  // Call handed off under the same drain+flag
          __hip_atomic_store(&CallL[n], creg, __ATOMIC_RELAXED,
                             __HIP_MEMORY_SCOPE_AGENT);
      }
    }
    asm volatile("s_waitcnt vmcnt(0)" ::: "memory");  // own stores acked
    __syncthreads();  // all waves' stores drained before publish
    if (tid == 0)
      __hip_atomic_store(&fown[blkid], t + 1, __ATOMIC_RELAXED,
                         __HIP_MEMORY_SCOPE_AGENT);
  }
}

// ---------------- epilogue ----------------
__global__ __launch_bounds__(256) void epilogue_out(
    const float* __restrict__ H7,   // [QQ, HPAD]
    const float* __restrict__ Wlin, const float* __restrict__ blin,
    const int* __restrict__ ccol, const float* __restrict__ Dnz,
    float* __restrict__ out,        // [QQ, NN]
    float* __restrict__ irbuf, float* __restrict__ mnirbuf) {
  int t = blockIdx.x, tid = threadIdx.x;
  int wave = tid >> 6, lane = tid & 63;
  __shared__ float hbuf[NN];
  __shared__ float smin[4], smax[4];
  __shared__ float bc[2];
  float lmin = 3.4e38f, lmax = -3.4e38f;
  for (int i = tid; i < NN; i += 256) {
    float v = H7[(size_t)t * HPAD + i];
    hbuf[i] = v;
    lmin = fminf(lmin, v); lmax = fmaxf(lmax, v);
  }
  lmin = wred_min(lmin); lmax = wred_max(lmax);
  if (lane == 0) { smin[wave] = lmin; smax[wave] = lmax; }
  __syncthreads();
  if (tid == 0) {
    bc[0] = fminf(fminf(smin[0], smin[1]), fminf(smin[2], smin[3]));
    bc[1] = fmaxf(fmaxf(smax[0], smax[1]), fmaxf(smax[2], smax[3]));
  }
  __syncthreads();
  float hmn = bc[0], hmx = bc[1];
  float clo = 3.4e38f, chi = -3.4e38f;
  if (tid < CCON) {
    float w = Wlin[tid], b = blin[tid];
    clo = b + fminf(w * hmn, w * hmx);
    chi = b + fmaxf(w * hmn, w * hmx);
  }
  clo = wred_min(clo); chi = wred_max(chi);
  __syncthreads();  // smin/smax reused below
  if (lane == 0) { smin[wave] = clo; smax[wave] = chi; }
  __syncthreads();
  if (tid == 0) {
    float mn = fminf(fminf(smin[0], smin[1]), fminf(smin[2], smin[3]));
    float mx = fmaxf(fmaxf(smax[0], smax[1]), fmaxf(smax[2], smax[3]));
    float ir = 1.f / (mx - mn);
    bc[0] = mn; bc[1] = ir;
    irbuf[t] = ir;
    mnirbuf[t] = mn * ir;
  }
  __syncthreads();
  float mn = bc[0], ir = bc[1];
  int cc = ccol[t];
  float wcc = Wlin[cc], bcc = blin[cc], d = Dnz[t];
  for (int n = tid; n < NN; n += 256) {
    float s = (hbuf[n] * wcc + bcc - mn) * ir;
    out[(size_t)t * NN + n] = fmaxf(0.25f, 1.f - expf(-10.f * (s - d)));
  }
}

__global__ void reduce_scalars(const float* __restrict__ ir,
                               const float* __restrict__ mnir,
                               float* __restrict__ scal) {
  int tid = threadIdx.x;  // 512
  int wave = tid >> 6, lane = tid & 63;
  __shared__ float s1[8], s2[8];
  float a = ir[tid], b = mnir[tid];
  a = wred_sum(a); b = wred_sum(b);
  if (lane == 0) { s1[wave] = a; s2[wave] = b; }
  __syncthreads();
  if (tid == 0) {
    float A = 0.f, B = 0.f;
    for (int i = 0; i < 8; i++) { A += s1[i]; B += s2[i]; }
    scal[0] = A; scal[1] = B;
  }
}

__global__ void accum_A(const float* __restrict__ H7,
                        const float* __restrict__ ir,
                        float* __restrict__ Avec) {
  int n = blockIdx.x * 256 + threadIdx.x;
  if (n < NN) {
    float acc = 0.f;
    for (int t = 0; t < QQ; t++) acc += H7[(size_t)t * HPAD + n] * ir[t];
    Avec[n] = acc;
  }
}

__global__ void skills_out(const float* __restrict__ Avec,
                           const float* __restrict__ Wlin,
                           const float* __restrict__ blin,
                           const float* __restrict__ scal,
                           float* __restrict__ out) {  // [NN, CCON]
  int idx = blockIdx.x * 256 + threadIdx.x;
  if (idx < NN * CCON) {
    int n = idx >> 7, c = idx & 127;
    out[idx] = (Wlin[c] * Avec[n] + blin[c] * scal[0] - scal[1]) * (1.f / (float)QQ);
  }
}

extern "C" void kernel_launch(void* const* d_in, const int* in_sizes, int n_in,
                              void* d_out, int out_size, void* d_ws, size_t ws_size,
                              hipStream_t stream) {
  const float* inputs = (const float*)d_in[0];
  const int*   ccol   = (const int*)d_in[1];
  const float* W_inp  = (const float*)d_in[2];
  const float* b_inp  = (const float*)d_in[3];
  const float* W_ih0  = (const float*)d_in[4];
  const float* W_hh0  = (const float*)d_in[5];
  const float* b_ih0  = (const float*)d_in[6];
  const float* b_hh0  = (const float*)d_in[7];
  const float* W_ih   = (const float*)d_in[8];   // [7, 4000, 1000]
  const float* W_hh   = (const float*)d_in[9];   // [7, 4000, 1000]
  const float* b_ih   = (const float*)d_in[10];  // [7, 4000]
  const float* b_hh   = (const float*)d_in[11];  // [7, 4000]
  const float* W_lin  = (const float*)d_in[12];  // [128]
  const float* b_lin  = (const float*)d_in[13];  // [128]
  const float* D_nz   = (const float*)d_in[14];  // [512]

  float* ws = (float*)d_ws;
  float* X    = ws;                           // [512,1024] padded rows
  float* H    = X + (size_t)QQ * HPAD;        // [8][512][1024]
  float* Call = H + (size_t)LAYERS * QQ * HPAD; // [8][1024]
  float* irb  = Call + LAYERS * HPAD;         // [512]
  float* mnir = irb + QQ;                     // [512]
  float* Avec = mnir + QQ;                    // [1024]
  float* scal = Avec + 1024;                  // [2] (+pad)
  int*   flags = (int*)(scal + 16);           // [8*64] stamped flags

  float* out_main   = (float*)d_out;            // [512,1000]
  float* out_skills = (float*)d_out + QQ * NN;  // [1000,128]

  // Zero all layer flags (captured in graph; re-zeroed every replay).
  hipMemsetAsync(flags, 0, LAYERS * 64 * sizeof(int), stream);

  // X = inputs @ W_inp^T + b_inp   (M=512, K=1000, R=1024, ldc=HPAD)
  gemm_nt<<<dim3(HPAD / 64, QQ / 64), 256, 0, stream>>>(
      inputs, W_inp, b_inp, X, QQ, NN, HPAD, NN, HPAD);

  // One self-timed launch: pairs in topological order (diagonal s=l+c asc,
  // deeper layer first within a diagonal).
  WaveArgs wa;
  wa.X = X; wa.Wih0 = W_ih0; wa.Whh0 = W_hh0; wa.bih0 = b_ih0; wa.bhh0 = b_hh0;
  wa.Wih7 = W_ih; wa.Whh7 = W_hh; wa.bih7 = b_ih; wa.bhh7 = b_hh;
  wa.H = H; wa.Call = Call; wa.flags = flags;
  {
    int idx = 0;
    for (int s = 0; s <= (LAYERS - 1) + (CHUNKS - 1); s++)
      for (int l = LAYERS - 1; l >= 0; l--) {
        int c = s - l;
        if (c < 0 || c >= CHUNKS) continue;
        wa.pl[idx] = l; wa.pc[idx] = c; idx++;
      }
  }
  lstm_wave<<<NPAIRS * LBLK, 1024, 0, stream>>>(wa);

  float* H7 = H + (size_t)7 * QQ * HPAD;
  epilogue_out<<<QQ, 256, 0, stream>>>(H7, W_lin, b_lin, ccol, D_nz,
                                       out_main, irb, mnir);
  reduce_scalars<<<1, 512, 0, stream>>>(irb, mnir, scal);
  accum_A<<<4, 256, 0, stream>>>(H7, irb, Avec);
  skills_out<<<(NN * CCON) / 256, 256, 0, stream>>>(Avec, W_lin, b_lin, scal,
                                                    out_skills);
}